// Round 1
// baseline (607.457 us; speedup 1.0000x reference)
//
#include <hip/hip_runtime.h>
#include <cstdint>

#define NB    32
#define NTOK  1024
#define D_    768
#define NHR   4096
#define HID   384
#define KSEL  154
#define MSEL  4928          // 32 * 154, divisible by 64 (77 tiles)
#define FLAT  3072
#define GIN   1537

// workspace layout (bytes)
#define OFF_SEL  0                    // int[4928]
#define OFF_H    (64*1024)            // f32[4928*384]  = 7.57 MB
#define OFF_RL   (8*1024*1024)        // f32[4928*768]  = 15.1 MB
#define OFF_HG   (24*1024*1024)       // f32[4928*384]  = 7.57 MB
// total ~32.8 MB

// ---------------- out = base (float4 copy) ----------------
__global__ __launch_bounds__(256) void copy_kernel(const float4* __restrict__ src,
                                                   float4* __restrict__ dst, int n4) {
    int i = blockIdx.x * 256 + threadIdx.x;
    int stride = gridDim.x * 256;
    for (; i < n4; i += stride) dst[i] = src[i];
}

// ---------------- top-k selection (per batch row) ----------------
// rank(t) = #{j: s[j] > s[t]} + #{j < t: s[j] == s[t]};  selected iff rank < KSEL.
// Matches jax.lax.top_k set (value desc, index asc tie-break). Exactly KSEL per batch.
__global__ __launch_bounds__(256) void topk_kernel(const float* __restrict__ scores,
                                                   int* __restrict__ sel) {
    __shared__ float s[NTOK];
    __shared__ int cnt;
    const int b = blockIdx.x;
    const float* sp = scores + b * NTOK;
    for (int i = threadIdx.x; i < NTOK; i += 256) s[i] = sp[i];
    if (threadIdx.x == 0) cnt = 0;
    __syncthreads();
    for (int t = threadIdx.x; t < NTOK; t += 256) {
        float v = s[t];
        int rank = 0;
        for (int j = 0; j < NTOK; ++j) {
            float vj = s[j];
            rank += (vj > v) || (vj == v && j < t);
        }
        if (rank < KSEL) {
            int pos = atomicAdd(&cnt, 1);
            sel[b * KSEL + pos] = t;
        }
    }
}

// ---------------- fused tiled GEMM over selected rows ----------------
// MODE 0: h  = GELU( gather(highres)[4928 x 3072] @ W1[3072x384] + b1 )
// MODE 1: rl = h[4928x384] @ W2[384x768] + b2
// MODE 2: hg = SiLU( [base_sel | rl | score][4928 x 1537] @ Wg1[1537x384] + bg1 )
// Tile: BM=64, BN=64, BK=32; 256 threads; each thread 4x4 outputs.
template <int MODE>
__global__ __launch_bounds__(256) void gemm_fused(
    const int* __restrict__ sel,
    const float* __restrict__ A0,      // mode0: highres; mode1: h; mode2: base
    const float* __restrict__ A1,      // mode2: rl
    const float* __restrict__ scores,  // mode2
    const float* __restrict__ W,
    const float* __restrict__ bias,
    float* __restrict__ Cout) {
    constexpr int K = (MODE == 0) ? FLAT : (MODE == 1) ? HID : GIN;
    constexpr int N = (MODE == 1) ? D_ : HID;

    __shared__ float As[64 * 33];        // padded: bank = (row + col) % 32
    __shared__ float Bs[32 * 64];
    __shared__ uint64_t off0[64 * 4];    // mode0: per-row patch base offsets
    __shared__ uint64_t boff[64];        // mode2: per-row base-token offset
    __shared__ float scv[64];            // mode2: per-row score

    const int tid = threadIdx.x;
    const int n0 = blockIdx.x * 64;
    const int m0 = blockIdx.y * 64;

    if (tid < 64) {
        int r = m0 + tid;
        int b = r / KSEL;
        if (MODE == 0) {
            int t = sel[r];
            int gy = t >> 5, gx = t & 31;
            #pragma unroll
            for (int p = 0; p < 4; ++p) {
                int hr = (gy * 2 + (p >> 1)) * 64 + gx * 2 + (p & 1);
                off0[tid * 4 + p] = ((uint64_t)b * NHR + hr) * D_;
            }
        } else if (MODE == 2) {
            int t = sel[r];
            boff[tid] = ((uint64_t)b * NTOK + t) * D_;
            scv[tid] = scores[b * NTOK + t];
        }
    }
    __syncthreads();

    const int q = tid >> 4;            // rows q, q+16, q+32, q+48
    const int c = (tid & 15) * 4;      // 4 consecutive cols
    float acc[4][4] = {};

    for (int k0 = 0; k0 < K; k0 += 32) {
        // ---- stage A tile: 64 rows x 32 cols (512 float4, 2 iters) ----
        #pragma unroll
        for (int it = 0; it < 2; ++it) {
            int idx = it * 256 + tid;
            int row = idx >> 3;
            int c4 = (idx & 7) * 4;
            float4 v;
            if (MODE == 0) {
                int p = k0 / D_;                 // 768 % 32 == 0 -> uniform per tile
                int kcol = k0 - p * D_ + c4;
                v = *(const float4*)(A0 + off0[row * 4 + p] + kcol);
            } else if (MODE == 1) {
                v = *(const float4*)(A0 + (uint64_t)(m0 + row) * HID + k0 + c4);
            } else {
                if (k0 < D_) {
                    v = *(const float4*)(A0 + boff[row] + k0 + c4);
                } else if (k0 < 2 * D_) {
                    v = *(const float4*)(A1 + (uint64_t)(m0 + row) * D_ + (k0 - D_) + c4);
                } else {  // k0 == 1536: only f==1536 (score) is valid
                    v = make_float4(c4 == 0 ? scv[row] : 0.f, 0.f, 0.f, 0.f);
                }
            }
            float* dst = &As[row * 33 + c4];
            dst[0] = v.x; dst[1] = v.y; dst[2] = v.z; dst[3] = v.w;
        }
        // ---- stage B tile: 32 rows x 64 cols (512 float4, 2 iters) ----
        #pragma unroll
        for (int it = 0; it < 2; ++it) {
            int idx = it * 256 + tid;
            int krow = idx >> 4;
            int c4 = (idx & 15) * 4;
            float4 v = make_float4(0.f, 0.f, 0.f, 0.f);
            if ((K % 32 == 0) || (k0 + krow < K))
                v = *(const float4*)(W + (uint64_t)(k0 + krow) * N + n0 + c4);
            *(float4*)&Bs[krow * 64 + c4] = v;
        }
        __syncthreads();
        // ---- compute ----
        #pragma unroll
        for (int kk = 0; kk < 32; ++kk) {
            float a0 = As[q * 33 + kk];
            float a1 = As[(q + 16) * 33 + kk];
            float a2 = As[(q + 32) * 33 + kk];
            float a3 = As[(q + 48) * 33 + kk];
            float4 bv = *(const float4*)&Bs[kk * 64 + c];
            acc[0][0] += a0 * bv.x; acc[0][1] += a0 * bv.y; acc[0][2] += a0 * bv.z; acc[0][3] += a0 * bv.w;
            acc[1][0] += a1 * bv.x; acc[1][1] += a1 * bv.y; acc[1][2] += a1 * bv.z; acc[1][3] += a1 * bv.w;
            acc[2][0] += a2 * bv.x; acc[2][1] += a2 * bv.y; acc[2][2] += a2 * bv.z; acc[2][3] += a2 * bv.w;
            acc[3][0] += a3 * bv.x; acc[3][1] += a3 * bv.y; acc[3][2] += a3 * bv.z; acc[3][3] += a3 * bv.w;
        }
        __syncthreads();
    }

    // ---- epilogue: bias + activation + store ----
    #pragma unroll
    for (int m = 0; m < 4; ++m) {
        int rg = m0 + q + 16 * m;
        float4 o;
        #pragma unroll
        for (int jj = 0; jj < 4; ++jj) {
            float x = acc[m][jj] + bias[n0 + c + jj];
            if (MODE == 0) {
                x = 0.5f * x * (1.0f + erff(x * 0.70710678118654752f));  // exact GELU
            } else if (MODE == 2) {
                x = x / (1.0f + __expf(-x));                              // SiLU
            }
            ((float*)&o)[jj] = x;
        }
        *(float4*)(Cout + (uint64_t)rg * N + n0 + c) = o;
    }
}

// ---------------- gate + blend (one wave per selected row) ----------------
__global__ __launch_bounds__(256) void blend_kernel(
    const int* __restrict__ sel,
    const float* __restrict__ hg,
    const float* __restrict__ Wg2, const float* __restrict__ bg2,
    const float* __restrict__ base, const float* __restrict__ rl,
    float* __restrict__ out) {
    const int wid = threadIdx.x >> 6;
    const int lane = threadIdx.x & 63;
    const int r = blockIdx.x * 4 + wid;  // MSEL % 4 == 0
    const int b = r / KSEL;
    const int t = sel[r];

    const float* hgr = hg + (uint64_t)r * HID;
    float sum = 0.f;
    #pragma unroll
    for (int i = 0; i < 6; ++i) sum += hgr[lane + 64 * i] * Wg2[lane + 64 * i];
    #pragma unroll
    for (int off = 32; off; off >>= 1) sum += __shfl_xor(sum, off);
    float gate = 1.0f / (1.0f + __expf(-(sum + bg2[0])));

    const uint64_t bo = ((uint64_t)b * NTOK + t) * D_;
    const float4* b4 = (const float4*)(base + bo);
    const float4* r4 = (const float4*)(rl + (uint64_t)r * D_);
    float4* o4 = (float4*)(out + bo);
    #pragma unroll
    for (int i = 0; i < 3; ++i) {
        int idx = lane + 64 * i;  // 768/4 = 192 = 64*3
        float4 bb = b4[idx], rr = r4[idx];
        float4 oo;
        oo.x = bb.x + gate * (rr.x - bb.x);
        oo.y = bb.y + gate * (rr.y - bb.y);
        oo.z = bb.z + gate * (rr.z - bb.z);
        oo.w = bb.w + gate * (rr.w - bb.w);
        o4[idx] = oo;
    }
}

extern "C" void kernel_launch(void* const* d_in, const int* in_sizes, int n_in,
                              void* d_out, int out_size, void* d_ws, size_t ws_size,
                              hipStream_t stream) {
    const float* base   = (const float*)d_in[0];
    const float* hires  = (const float*)d_in[1];
    const float* scores = (const float*)d_in[2];
    const float* W1  = (const float*)d_in[3];
    const float* b1  = (const float*)d_in[4];
    const float* W2  = (const float*)d_in[5];
    const float* b2  = (const float*)d_in[6];
    const float* Wg1 = (const float*)d_in[7];
    const float* bg1 = (const float*)d_in[8];
    const float* Wg2 = (const float*)d_in[9];
    const float* bg2 = (const float*)d_in[10];
    float* out = (float*)d_out;

    char* ws = (char*)d_ws;
    int*   sel = (int*)(ws + OFF_SEL);
    float* h   = (float*)(ws + OFF_H);
    float* rl  = (float*)(ws + OFF_RL);
    float* hg  = (float*)(ws + OFF_HG);

    const int n4 = NB * NTOK * D_ / 4;
    copy_kernel<<<dim3(1024), dim3(256), 0, stream>>>((const float4*)base, (float4*)out, n4);
    topk_kernel<<<dim3(NB), dim3(256), 0, stream>>>(scores, sel);
    gemm_fused<0><<<dim3(HID / 64, MSEL / 64), dim3(256), 0, stream>>>(sel, hires, nullptr, nullptr, W1, b1, h);
    gemm_fused<1><<<dim3(D_ / 64, MSEL / 64), dim3(256), 0, stream>>>(sel, h, nullptr, nullptr, W2, b2, rl);
    gemm_fused<2><<<dim3(HID / 64, MSEL / 64), dim3(256), 0, stream>>>(sel, base, rl, scores, Wg1, bg1, hg);
    blend_kernel<<<dim3(MSEL / 4), dim3(256), 0, stream>>>(sel, hg, Wg2, bg2, base, rl, out);
}

// Round 2
// 232.863 us; speedup vs baseline: 2.6086x; 2.6086x over previous
//
#include <hip/hip_runtime.h>
#include <cstdint>

#define NB    32
#define NTOK  1024
#define D_    768
#define NHR   4096
#define HID   384
#define KSEL  154
#define MSEL  4928          // 32*154 = 77 * 64
#define FLAT  3072

typedef short  s16x8 __attribute__((ext_vector_type(8)));
typedef unsigned short u16x8 __attribute__((ext_vector_type(8)));
typedef unsigned short u16x4 __attribute__((ext_vector_type(4)));
typedef float  f32x4 __attribute__((ext_vector_type(4)));

__device__ inline unsigned short f2bf(float f) {
    uint32_t u = __builtin_bit_cast(uint32_t, f);
    u += 0x7FFFu + ((u >> 16) & 1u);          // round-to-nearest-even
    return (unsigned short)(u >> 16);
}
__device__ inline float bf2f(unsigned short h) {
    uint32_t u = ((uint32_t)h) << 16;
    return __builtin_bit_cast(float, u);
}

// ---- workspace layout (bytes); Aloc bf16[4928][3072] lives in d_out scratch ----
#define OFF_SEL   0              // int[4928]
#define OFF_W1T   32768          // bf16 [384][3072]   2359296 B
#define OFF_W2T   2392064        // bf16 [768][384]     589824 B
#define OFF_WG1T  2981888        // bf16 [384][1536]   1179648 B
#define OFF_ABASE 4161536        // bf16 [4928][768]   7569408 B
#define OFF_H     11730944       // bf16 [4928][384]   3784704 B
#define OFF_RL    15515648       // bf16 [4928][768]   7569408 B
#define OFF_HG    23085056       // f32  [4928][384]   7569408 B  (ends ~30.7 MB)

// ---------------- out = base ----------------
__global__ __launch_bounds__(256) void copy_kernel(const float4* __restrict__ src,
                                                   float4* __restrict__ dst, int n4) {
    int i = blockIdx.x * 256 + threadIdx.x;
    int stride = gridDim.x * 256;
    for (; i < n4; i += stride) dst[i] = src[i];
}

// ---------------- top-k (matches lax.top_k tie-break) ----------------
__global__ __launch_bounds__(256) void topk_kernel(const float* __restrict__ scores,
                                                   int* __restrict__ sel) {
    __shared__ float s[NTOK];
    __shared__ int cnt;
    const int b = blockIdx.x;
    const float* sp = scores + b * NTOK;
    for (int i = threadIdx.x; i < NTOK; i += 256) s[i] = sp[i];
    if (threadIdx.x == 0) cnt = 0;
    __syncthreads();
    for (int t = threadIdx.x; t < NTOK; t += 256) {
        float v = s[t];
        int rank = 0;
        for (int j = 0; j < NTOK; ++j) {
            float vj = s[j];
            rank += (vj > v) || (vj == v && j < t);
        }
        if (rank < KSEL) {
            int pos = atomicAdd(&cnt, 1);
            sel[b * KSEL + pos] = t;
        }
    }
}

// ---------------- transpose + f32->bf16: dst[n][k] = src[k][n] ----------------
__global__ __launch_bounds__(256) void tcvt_kernel(const float* __restrict__ src,
                                                   unsigned short* __restrict__ dst,
                                                   int K, int N) {
    const int n  = blockIdx.x * 64 + (threadIdx.x & 63);
    const int k0 = blockIdx.y * 64 + (threadIdx.x >> 6) * 16;
    unsigned short tmp[16];
    #pragma unroll
    for (int j = 0; j < 16; ++j) tmp[j] = f2bf(src[(uint64_t)(k0 + j) * N + n]);
    #pragma unroll
    for (int h = 0; h < 2; ++h) {
        u16x8 v;
        #pragma unroll
        for (int p = 0; p < 8; ++p) v[p] = tmp[h * 8 + p];
        *(u16x8*)(dst + (uint64_t)n * K + k0 + h * 8) = v;
    }
}

// ---------------- gather selected rows -> bf16 Aloc (patches) + Abase ----------------
__global__ __launch_bounds__(256) void gather_kernel(
    const int* __restrict__ sel, const float* __restrict__ highres,
    const float* __restrict__ base,
    unsigned short* __restrict__ Aloc, unsigned short* __restrict__ Abase) {
    const int r = blockIdx.x;
    const int b = r / KSEL;
    const int t = sel[r];
    const int gy = t >> 5, gx = t & 31;
    for (int ch = threadIdx.x; ch < 480; ch += 256) {
        if (ch < 384) {
            int k8 = ch * 8;
            int p = k8 / D_;
            int col = k8 - p * D_;
            int hr = (gy * 2 + (p >> 1)) * 64 + gx * 2 + (p & 1);
            const float4* s4 = (const float4*)(highres + ((uint64_t)b * NHR + hr) * D_ + col);
            float4 v0 = s4[0], v1 = s4[1];
            u16x8 v;
            v[0]=f2bf(v0.x); v[1]=f2bf(v0.y); v[2]=f2bf(v0.z); v[3]=f2bf(v0.w);
            v[4]=f2bf(v1.x); v[5]=f2bf(v1.y); v[6]=f2bf(v1.z); v[7]=f2bf(v1.w);
            *(u16x8*)(Aloc + (uint64_t)r * FLAT + k8) = v;
        } else {
            int col = (ch - 384) * 8;
            const float4* s4 = (const float4*)(base + ((uint64_t)b * NTOK + t) * D_ + col);
            float4 v0 = s4[0], v1 = s4[1];
            u16x8 v;
            v[0]=f2bf(v0.x); v[1]=f2bf(v0.y); v[2]=f2bf(v0.z); v[3]=f2bf(v0.w);
            v[4]=f2bf(v1.x); v[5]=f2bf(v1.y); v[6]=f2bf(v1.z); v[7]=f2bf(v1.w);
            *(u16x8*)(Abase + (uint64_t)r * D_ + col) = v;
        }
    }
}

// ---------------- MFMA GEMM: BM=BN=64, BK=64, 4 waves (2x2) of 32x32 ----------------
// MODE 0: h  = GELU(Aloc[4928x3072] @ W1t) bf16 out
// MODE 1: rl = h[4928x384] @ W2t           bf16 out
// MODE 2: hg = SiLU([Abase|rl] @ Wg1t + score*Wg1[1536] + bg1) f32 out
template <int MODE>
__global__ __launch_bounds__(256) void gemm_mfma(
    const unsigned short* __restrict__ A0,
    const unsigned short* __restrict__ A1,
    const unsigned short* __restrict__ Bt,
    const float* __restrict__ bias,
    const int* __restrict__ sel,
    const float* __restrict__ scores,
    const float* __restrict__ WgLast,
    void* __restrict__ Cout)
{
    constexpr int K = MODE == 0 ? FLAT : (MODE == 1 ? HID : 2 * D_);
    constexpr int N = MODE == 1 ? D_ : HID;
    constexpr int NSTEP = K / 64;

    __shared__ unsigned short As[2][64 * 64];
    __shared__ unsigned short Bs[2][64 * 64];
    __shared__ float scv[64];

    const int tid = threadIdx.x;
    const int lane = tid & 63;
    const int wid = tid >> 6;
    const int wm = wid >> 1;
    const int wn = wid & 1;
    const int m0 = blockIdx.y * 64;
    const int n0 = blockIdx.x * 64;

    if (MODE == 2 && tid < 64) {
        int r = m0 + tid, b = r / KSEL, t = sel[r];
        scv[tid] = scores[b * NTOK + t];
    }

    const int sr0 = tid >> 3;   // row 0..31 (+32 for second half)
    const int sc0 = tid & 7;    // 16B chunk 0..7

    auto loadA = [&](int k0, int half, s16x8& dst) {
        int r = sr0 + half * 32;
        int k = k0 + sc0 * 8;
        const unsigned short* p;
        if (MODE == 2) {
            p = (k < D_) ? (A0 + (uint64_t)(m0 + r) * D_ + k)
                         : (A1 + (uint64_t)(m0 + r) * D_ + (k - D_));
        } else {
            p = A0 + (uint64_t)(m0 + r) * K + k;
        }
        dst = *(const s16x8*)p;
    };
    auto loadB = [&](int k0, int half, s16x8& dst) {
        int r = sr0 + half * 32;
        dst = *(const s16x8*)(Bt + (uint64_t)(n0 + r) * K + k0 + sc0 * 8);
    };
    auto writeTile = [&](int buf, s16x8* a, s16x8* b) {
        #pragma unroll
        for (int half = 0; half < 2; ++half) {
            int r = sr0 + half * 32;
            int c = sc0 ^ (r & 7);                 // XOR swizzle (write side)
            *(s16x8*)&As[buf][r * 64 + c * 8] = a[half];
            *(s16x8*)&Bs[buf][r * 64 + c * 8] = b[half];
        }
    };

    f32x4 acc[2][2];
    #pragma unroll
    for (int i = 0; i < 2; ++i)
        #pragma unroll
        for (int j = 0; j < 2; ++j) acc[i][j] = (f32x4){0.f, 0.f, 0.f, 0.f};

    s16x8 aR[2], bR[2];
    loadA(0, 0, aR[0]); loadA(0, 1, aR[1]);
    loadB(0, 0, bR[0]); loadB(0, 1, bR[1]);
    writeTile(0, aR, bR);
    __syncthreads();
    if (NSTEP > 1) {
        loadA(64, 0, aR[0]); loadA(64, 1, aR[1]);
        loadB(64, 0, bR[0]); loadB(64, 1, bR[1]);
    }

    int cur = 0;
    for (int t = 0; t < NSTEP; ++t) {
        #pragma unroll
        for (int kk = 0; kk < 2; ++kk) {
            s16x8 af[2], bf[2];
            #pragma unroll
            for (int i = 0; i < 2; ++i) {
                int row  = wm * 32 + i * 16 + (lane & 15);
                int cch  = (kk * 4 + (lane >> 4)) ^ (row & 7);   // XOR swizzle (read side)
                af[i] = *(const s16x8*)&As[cur][row * 64 + cch * 8];
                int nrow = wn * 32 + i * 16 + (lane & 15);
                int cchb = (kk * 4 + (lane >> 4)) ^ (nrow & 7);
                bf[i] = *(const s16x8*)&Bs[cur][nrow * 64 + cchb * 8];
            }
            #pragma unroll
            for (int i = 0; i < 2; ++i)
                #pragma unroll
                for (int j = 0; j < 2; ++j)
                    acc[i][j] = __builtin_amdgcn_mfma_f32_16x16x32_bf16(af[i], bf[j], acc[i][j], 0, 0, 0);
        }
        if (t + 1 < NSTEP) {
            writeTile(cur ^ 1, aR, bR);
            __syncthreads();
            if (t + 2 < NSTEP) {
                int k0 = (t + 2) * 64;
                loadA(k0, 0, aR[0]); loadA(k0, 1, aR[1]);
                loadB(k0, 0, bR[0]); loadB(k0, 1, bR[1]);
            }
            cur ^= 1;
        }
    }

    // epilogue: C row = (lane>>4)*4+reg, col = lane&15 (m89-verified layout)
    #pragma unroll
    for (int i = 0; i < 2; ++i) {
        #pragma unroll
        for (int j = 0; j < 2; ++j) {
            #pragma unroll
            for (int reg = 0; reg < 4; ++reg) {
                int m = m0 + wm * 32 + i * 16 + (lane >> 4) * 4 + reg;
                int n = n0 + wn * 32 + j * 16 + (lane & 15);
                float x = acc[i][j][reg] + bias[n];
                if (MODE == 0) {
                    x = 0.5f * x * (1.0f + erff(x * 0.70710678118654752f));
                    ((unsigned short*)Cout)[(uint64_t)m * HID + n] = f2bf(x);
                } else if (MODE == 1) {
                    ((unsigned short*)Cout)[(uint64_t)m * D_ + n] = f2bf(x);
                } else {
                    x += scv[m - m0] * WgLast[n];
                    x = x / (1.0f + __expf(-x));
                    ((float*)Cout)[(uint64_t)m * HID + n] = x;
                }
            }
        }
    }
}

// ---------------- gate dot + blend (one wave per selected row) ----------------
__global__ __launch_bounds__(256) void blend_kernel(
    const int* __restrict__ sel, const float* __restrict__ hg,
    const float* __restrict__ Wg2, const float* __restrict__ bg2,
    const float* __restrict__ base, const unsigned short* __restrict__ rl,
    float* __restrict__ out)
{
    const int wid2 = threadIdx.x >> 6;
    const int lane = threadIdx.x & 63;
    const int r = blockIdx.x * 4 + wid2;   // MSEL % 4 == 0
    const int b = r / KSEL;
    const int t = sel[r];

    const float* hgr = hg + (uint64_t)r * HID;
    float sum = 0.f;
    #pragma unroll
    for (int i = 0; i < 6; ++i) sum += hgr[lane + 64 * i] * Wg2[lane + 64 * i];
    #pragma unroll
    for (int off = 32; off; off >>= 1) sum += __shfl_xor(sum, off);
    float gate = 1.0f / (1.0f + __expf(-(sum + bg2[0])));

    const uint64_t bo = ((uint64_t)b * NTOK + t) * D_;
    const float4* b4 = (const float4*)(base + bo);
    const u16x4* r4 = (const u16x4*)(rl + (uint64_t)r * D_);
    float4* o4 = (float4*)(out + bo);
    #pragma unroll
    for (int i = 0; i < 3; ++i) {
        int idx = lane + 64 * i;
        float4 bb = b4[idx];
        u16x4 rr = r4[idx];
        float4 oo;
        oo.x = bb.x + gate * (bf2f(rr[0]) - bb.x);
        oo.y = bb.y + gate * (bf2f(rr[1]) - bb.y);
        oo.z = bb.z + gate * (bf2f(rr[2]) - bb.z);
        oo.w = bb.w + gate * (bf2f(rr[3]) - bb.w);
        o4[idx] = oo;
    }
}

extern "C" void kernel_launch(void* const* d_in, const int* in_sizes, int n_in,
                              void* d_out, int out_size, void* d_ws, size_t ws_size,
                              hipStream_t stream) {
    const float* base   = (const float*)d_in[0];
    const float* hires  = (const float*)d_in[1];
    const float* scores = (const float*)d_in[2];
    const float* W1  = (const float*)d_in[3];
    const float* b1  = (const float*)d_in[4];
    const float* W2  = (const float*)d_in[5];
    const float* b2  = (const float*)d_in[6];
    const float* Wg1 = (const float*)d_in[7];
    const float* bg1 = (const float*)d_in[8];
    const float* Wg2 = (const float*)d_in[9];
    const float* bg2 = (const float*)d_in[10];
    float* out = (float*)d_out;

    char* ws = (char*)d_ws;
    int*            sel   = (int*)(ws + OFF_SEL);
    unsigned short* W1t   = (unsigned short*)(ws + OFF_W1T);
    unsigned short* W2t   = (unsigned short*)(ws + OFF_W2T);
    unsigned short* Wg1t  = (unsigned short*)(ws + OFF_WG1T);
    unsigned short* Abase = (unsigned short*)(ws + OFF_ABASE);
    unsigned short* h     = (unsigned short*)(ws + OFF_H);
    unsigned short* rl    = (unsigned short*)(ws + OFF_RL);
    float*          hg    = (float*)(ws + OFF_HG);
    unsigned short* Aloc  = (unsigned short*)d_out;   // scratch until copy_kernel

    topk_kernel<<<dim3(NB), dim3(256), 0, stream>>>(scores, sel);
    tcvt_kernel<<<dim3(HID / 64, FLAT / 64), dim3(256), 0, stream>>>(W1, W1t, FLAT, HID);
    tcvt_kernel<<<dim3(D_ / 64, HID / 64), dim3(256), 0, stream>>>(W2, W2t, HID, D_);
    tcvt_kernel<<<dim3(HID / 64, (2 * D_) / 64), dim3(256), 0, stream>>>(Wg1, Wg1t, 2 * D_, HID);
    gather_kernel<<<dim3(MSEL), dim3(256), 0, stream>>>(sel, hires, base, Aloc, Abase);
    gemm_mfma<0><<<dim3(HID / 64, MSEL / 64), dim3(256), 0, stream>>>(Aloc, nullptr, W1t, b1, sel, scores, nullptr, h);
    gemm_mfma<1><<<dim3(D_ / 64, MSEL / 64), dim3(256), 0, stream>>>(h, nullptr, W2t, b2, sel, scores, nullptr, rl);
    gemm_mfma<2><<<dim3(HID / 64, MSEL / 64), dim3(256), 0, stream>>>(Abase, rl, Wg1t, bg1, sel, scores, Wg1 + (uint64_t)1536 * HID, hg);
    const int n4 = NB * NTOK * D_ / 4;
    copy_kernel<<<dim3(1024), dim3(256), 0, stream>>>((const float4*)base, (float4*)out, n4);
    blend_kernel<<<dim3(MSEL / 4), dim3(256), 0, stream>>>(sel, hg, Wg2, bg2, base, rl, out);
}

// Round 3
// 153.373 us; speedup vs baseline: 3.9607x; 1.5183x over previous
//
#include <hip/hip_runtime.h>
#include <cstdint>

#define NB    32
#define NTOK  1024
#define D_    768
#define NHR   4096
#define HID   384
#define KSEL  154
#define MSEL  4928          // 32*154 = 77 * 64
#define MT_   77            // m-tiles of 64
#define FLAT  3072

typedef short  s16x8 __attribute__((ext_vector_type(8)));
typedef unsigned short u16x8 __attribute__((ext_vector_type(8)));
typedef unsigned short u16x4 __attribute__((ext_vector_type(4)));
typedef float  f32x4 __attribute__((ext_vector_type(4)));

__device__ inline unsigned short f2bf(float f) {
    uint32_t u = __builtin_bit_cast(uint32_t, f);
    u += 0x7FFFu + ((u >> 16) & 1u);          // RNE
    return (unsigned short)(u >> 16);
}
__device__ inline float bf2f(unsigned short h) {
    uint32_t u = ((uint32_t)h) << 16;
    return __builtin_bit_cast(float, u);
}

// ---- workspace layout (bytes); Aloc bf16[4928][3072] lives in d_out scratch ----
#define OFF_SEL   0              // int[4928]
#define OFF_W1T   32768          // bf16 [384][3072]   2359296 B
#define OFF_W2T   2392064        // bf16 [768][384]     589824 B
#define OFF_WG1T  2981888        // bf16 [384][1536]   1179648 B
#define OFF_ABASE 4161536        // bf16 [4928][768]   7569408 B
#define OFF_H     11730944       // bf16 [4928][384]   3784704 B
#define OFF_RL    15515648       // bf16 [4928][768]   7569408 B
#define OFF_HG    23085056       // f32  [4928][384]   7569408 B
#define OFF_RMAP  30654464       // int  [32768]        131072 B (ends ~30.8 MB)

// ---------------- top-k + inverse map (1024 thr, 1 token each) ----------------
__global__ __launch_bounds__(1024) void topk_kernel(const float* __restrict__ scores,
                                                    int* __restrict__ sel,
                                                    int* __restrict__ rmap) {
    __shared__ float s[NTOK];
    __shared__ int cnt;
    const int b = blockIdx.x;
    const int t = threadIdx.x;
    s[t] = scores[b * NTOK + t];
    if (t == 0) cnt = 0;
    __syncthreads();
    float v = s[t];
    int rank = 0;
    for (int j = 0; j < NTOK; ++j) {
        float vj = s[j];
        rank += (vj > v) || (vj == v && j < t);
    }
    int rm = -1;
    if (rank < KSEL) {
        int pos = atomicAdd(&cnt, 1);
        rm = b * KSEL + pos;
        sel[rm] = t;
    }
    rmap[b * NTOK + t] = rm;
}

// ---------------- fused transpose+cvt for W1,W2,Wg1 (LDS transpose) ----------------
__global__ __launch_bounds__(256) void tcvt_all(const float* __restrict__ W1,
                                                const float* __restrict__ W2,
                                                const float* __restrict__ Wg1,
                                                unsigned short* __restrict__ W1t,
                                                unsigned short* __restrict__ W2t,
                                                unsigned short* __restrict__ Wg1t) {
    __shared__ unsigned short T[64][66];
    int bid = blockIdx.x;
    const float* src; unsigned short* dst; int K, N, kt, nt;
    if (bid < 288)      { src = W1;  dst = W1t;  K = FLAT;   N = HID; nt = bid % 6;  kt = bid / 6;  }
    else if (bid < 360) { int l = bid - 288; src = W2;  dst = W2t;  K = HID;  N = D_;  nt = l % 12; kt = l / 12; }
    else                { int l = bid - 360; src = Wg1; dst = Wg1t; K = 1536; N = HID; nt = l % 6;  kt = l / 6;  }
    const int k0 = kt * 64, n0 = nt * 64;
    const int tid = threadIdx.x;
    {
        const int ln = tid & 63, kc = tid >> 6;
        #pragma unroll
        for (int j = 0; j < 16; ++j)
            T[ln][kc * 16 + j] = f2bf(src[(uint64_t)(k0 + kc * 16 + j) * N + n0 + ln]);
    }
    __syncthreads();
    {
        const int row = tid >> 2, c0 = (tid & 3) * 16;
        u16x8 v0, v1;
        #pragma unroll
        for (int p = 0; p < 8; ++p) { v0[p] = T[row][c0 + p]; v1[p] = T[row][c0 + 8 + p]; }
        *(u16x8*)(dst + (uint64_t)(n0 + row) * K + k0 + c0) = v0;
        *(u16x8*)(dst + (uint64_t)(n0 + row) * K + k0 + c0 + 8) = v1;
    }
}

// ---------------- gather selected rows -> bf16 Aloc (patches) + Abase ----------------
__global__ __launch_bounds__(256) void gather_kernel(
    const int* __restrict__ sel, const float* __restrict__ highres,
    const float* __restrict__ base,
    unsigned short* __restrict__ Aloc, unsigned short* __restrict__ Abase) {
    const int r = blockIdx.x;
    const int b = r / KSEL;
    const int t = sel[r];
    const int gy = t >> 5, gx = t & 31;
    for (int ch = threadIdx.x; ch < 480; ch += 256) {
        if (ch < 384) {
            int k8 = ch * 8;
            int p = k8 / D_;
            int col = k8 - p * D_;
            int hr = (gy * 2 + (p >> 1)) * 64 + gx * 2 + (p & 1);
            const float4* s4 = (const float4*)(highres + ((uint64_t)b * NHR + hr) * D_ + col);
            float4 v0 = s4[0], v1 = s4[1];
            u16x8 v;
            v[0]=f2bf(v0.x); v[1]=f2bf(v0.y); v[2]=f2bf(v0.z); v[3]=f2bf(v0.w);
            v[4]=f2bf(v1.x); v[5]=f2bf(v1.y); v[6]=f2bf(v1.z); v[7]=f2bf(v1.w);
            *(u16x8*)(Aloc + (uint64_t)r * FLAT + k8) = v;
        } else {
            int col = (ch - 384) * 8;
            const float4* s4 = (const float4*)(base + ((uint64_t)b * NTOK + t) * D_ + col);
            float4 v0 = s4[0], v1 = s4[1];
            u16x8 v;
            v[0]=f2bf(v0.x); v[1]=f2bf(v0.y); v[2]=f2bf(v0.z); v[3]=f2bf(v0.w);
            v[4]=f2bf(v1.x); v[5]=f2bf(v1.y); v[6]=f2bf(v1.z); v[7]=f2bf(v1.w);
            *(u16x8*)(Abase + (uint64_t)r * D_ + col) = v;
        }
    }
}

// ---------------- MFMA GEMM: 64x64x64 tiles, 4 waves (2x2), XCD-grouped ----------------
// MODE 0: h  = GELU(Aloc[4928x3072] @ W1t) bf16 out
// MODE 1: rl = h[4928x384] @ W2t           bf16 out
// MODE 2: hg = SiLU([Abase|rl] @ Wg1t + score*Wg1[1536] + bg1) f32 out
template <int MODE>
__global__ __launch_bounds__(256) void gemm_mfma(
    const unsigned short* __restrict__ A0,
    const unsigned short* __restrict__ A1,
    const unsigned short* __restrict__ Bt,
    const float* __restrict__ bias,
    const int* __restrict__ sel,
    const float* __restrict__ scores,
    const float* __restrict__ WgLast,
    void* __restrict__ Cout)
{
    constexpr int K = MODE == 0 ? FLAT : (MODE == 1 ? HID : 2 * D_);
    constexpr int N = MODE == 1 ? D_ : HID;
    constexpr int NT = N / 64;
    constexpr int NSTEP = K / 64;

    // XCD-grouping: same m-tile -> same XCD (lin%8), consecutive n temporally adjacent
    const int lin = blockIdx.x;
    const int xcd = lin & 7;
    const int j   = lin >> 3;
    const int mhi = j / NT;
    const int ntile = j - mhi * NT;
    const int mt = mhi * 8 + xcd;
    if (mt >= MT_) return;
    const int m0 = mt * 64;
    const int n0 = ntile * 64;

    __shared__ unsigned short As[2][64 * 64];
    __shared__ unsigned short Bs[2][64 * 64];
    __shared__ float scv[64];

    const int tid = threadIdx.x;
    const int lane = tid & 63;
    const int wid = tid >> 6;
    const int wm = wid >> 1;
    const int wn = wid & 1;

    if (MODE == 2 && tid < 64) {
        int r = m0 + tid, b = r / KSEL, t = sel[r];
        scv[tid] = scores[b * NTOK + t];
    }

    const int sr0 = tid >> 3;   // row 0..31 (+32 for second half)
    const int sc0 = tid & 7;    // 16B chunk 0..7

    auto loadA = [&](int k0, int half, s16x8& dst) {
        int r = sr0 + half * 32;
        int k = k0 + sc0 * 8;
        const unsigned short* p;
        if (MODE == 2) {
            p = (k < D_) ? (A0 + (uint64_t)(m0 + r) * D_ + k)
                         : (A1 + (uint64_t)(m0 + r) * D_ + (k - D_));
        } else {
            p = A0 + (uint64_t)(m0 + r) * K + k;
        }
        dst = *(const s16x8*)p;
    };
    auto loadB = [&](int k0, int half, s16x8& dst) {
        int r = sr0 + half * 32;
        dst = *(const s16x8*)(Bt + (uint64_t)(n0 + r) * K + k0 + sc0 * 8);
    };
    auto writeTile = [&](int buf, s16x8* a, s16x8* b) {
        #pragma unroll
        for (int half = 0; half < 2; ++half) {
            int r = sr0 + half * 32;
            int c = sc0 ^ (r & 7);                 // XOR swizzle (write side)
            *(s16x8*)&As[buf][r * 64 + c * 8] = a[half];
            *(s16x8*)&Bs[buf][r * 64 + c * 8] = b[half];
        }
    };

    f32x4 acc[2][2];
    #pragma unroll
    for (int i = 0; i < 2; ++i)
        #pragma unroll
        for (int jj = 0; jj < 2; ++jj) acc[i][jj] = (f32x4){0.f, 0.f, 0.f, 0.f};

    s16x8 aR[2], bR[2];
    loadA(0, 0, aR[0]); loadA(0, 1, aR[1]);
    loadB(0, 0, bR[0]); loadB(0, 1, bR[1]);
    writeTile(0, aR, bR);
    __syncthreads();
    if (NSTEP > 1) {
        loadA(64, 0, aR[0]); loadA(64, 1, aR[1]);
        loadB(64, 0, bR[0]); loadB(64, 1, bR[1]);
    }

    int cur = 0;
    for (int t = 0; t < NSTEP; ++t) {
        #pragma unroll
        for (int kk = 0; kk < 2; ++kk) {
            s16x8 af[2], bfr[2];
            #pragma unroll
            for (int i = 0; i < 2; ++i) {
                int row  = wm * 32 + i * 16 + (lane & 15);
                int cch  = (kk * 4 + (lane >> 4)) ^ (row & 7);   // XOR swizzle (read side)
                af[i] = *(const s16x8*)&As[cur][row * 64 + cch * 8];
                int nrow = wn * 32 + i * 16 + (lane & 15);
                int cchb = (kk * 4 + (lane >> 4)) ^ (nrow & 7);
                bfr[i] = *(const s16x8*)&Bs[cur][nrow * 64 + cchb * 8];
            }
            #pragma unroll
            for (int i = 0; i < 2; ++i)
                #pragma unroll
                for (int jj = 0; jj < 2; ++jj)
                    acc[i][jj] = __builtin_amdgcn_mfma_f32_16x16x32_bf16(af[i], bfr[jj], acc[i][jj], 0, 0, 0);
        }
        if (t + 1 < NSTEP) {
            writeTile(cur ^ 1, aR, bR);
            __syncthreads();
            if (t + 2 < NSTEP) {
                int k0 = (t + 2) * 64;
                loadA(k0, 0, aR[0]); loadA(k0, 1, aR[1]);
                loadB(k0, 0, bR[0]); loadB(k0, 1, bR[1]);
            }
            cur ^= 1;
        }
    }

    // epilogue: C row = (lane>>4)*4+reg, col = lane&15
    #pragma unroll
    for (int i = 0; i < 2; ++i) {
        #pragma unroll
        for (int jj = 0; jj < 2; ++jj) {
            #pragma unroll
            for (int reg = 0; reg < 4; ++reg) {
                int m = m0 + wm * 32 + i * 16 + (lane >> 4) * 4 + reg;
                int n = n0 + wn * 32 + jj * 16 + (lane & 15);
                float x = acc[i][jj][reg] + bias[n];
                if (MODE == 0) {
                    x = 0.5f * x * (1.0f + erff(x * 0.70710678118654752f));
                    ((unsigned short*)Cout)[(uint64_t)m * HID + n] = f2bf(x);
                } else if (MODE == 1) {
                    ((unsigned short*)Cout)[(uint64_t)m * D_ + n] = f2bf(x);
                } else {
                    x += scv[m - m0] * WgLast[n];
                    x = x / (1.0f + __expf(-x));
                    ((float*)Cout)[(uint64_t)m * HID + n] = x;
                }
            }
        }
    }
}

// ---------------- finalize: out = base, blended on selected rows ----------------
__global__ __launch_bounds__(256) void finalize_kernel(
    const int* __restrict__ rmap,
    const float* __restrict__ hg,
    const float* __restrict__ Wg2, const float* __restrict__ bg2,
    const float* __restrict__ base, const unsigned short* __restrict__ rl,
    float* __restrict__ out)
{
    const int lane = threadIdx.x & 63;
    const int row = blockIdx.x * 4 + (threadIdx.x >> 6);  // 0..32767
    const int rm = rmap[row];

    const uint64_t bo = (uint64_t)row * D_;
    const float4* b4 = (const float4*)(base + bo);
    float4* o4 = (float4*)(out + bo);

    if (rm < 0) {
        #pragma unroll
        for (int i = 0; i < 3; ++i) o4[lane + 64 * i] = b4[lane + 64 * i];
        return;
    }
    const float* hgr = hg + (uint64_t)rm * HID;
    float sum = 0.f;
    #pragma unroll
    for (int i = 0; i < 6; ++i) sum += hgr[lane + 64 * i] * Wg2[lane + 64 * i];
    #pragma unroll
    for (int off = 32; off; off >>= 1) sum += __shfl_xor(sum, off);
    float gate = 1.0f / (1.0f + __expf(-(sum + bg2[0])));

    const u16x4* r4 = (const u16x4*)(rl + (uint64_t)rm * D_);
    #pragma unroll
    for (int i = 0; i < 3; ++i) {
        int idx = lane + 64 * i;
        float4 bb = b4[idx];
        u16x4 rr = r4[idx];
        float4 oo;
        oo.x = bb.x + gate * (bf2f(rr[0]) - bb.x);
        oo.y = bb.y + gate * (bf2f(rr[1]) - bb.y);
        oo.z = bb.z + gate * (bf2f(rr[2]) - bb.z);
        oo.w = bb.w + gate * (bf2f(rr[3]) - bb.w);
        o4[idx] = oo;
    }
}

extern "C" void kernel_launch(void* const* d_in, const int* in_sizes, int n_in,
                              void* d_out, int out_size, void* d_ws, size_t ws_size,
                              hipStream_t stream) {
    const float* base   = (const float*)d_in[0];
    const float* hires  = (const float*)d_in[1];
    const float* scores = (const float*)d_in[2];
    const float* W1  = (const float*)d_in[3];
    const float* b1  = (const float*)d_in[4];
    const float* W2  = (const float*)d_in[5];
    const float* b2  = (const float*)d_in[6];
    const float* Wg1 = (const float*)d_in[7];
    const float* bg1 = (const float*)d_in[8];
    const float* Wg2 = (const float*)d_in[9];
    const float* bg2 = (const float*)d_in[10];
    float* out = (float*)d_out;

    char* ws = (char*)d_ws;
    int*            sel   = (int*)(ws + OFF_SEL);
    unsigned short* W1t   = (unsigned short*)(ws + OFF_W1T);
    unsigned short* W2t   = (unsigned short*)(ws + OFF_W2T);
    unsigned short* Wg1t  = (unsigned short*)(ws + OFF_WG1T);
    unsigned short* Abase = (unsigned short*)(ws + OFF_ABASE);
    unsigned short* h     = (unsigned short*)(ws + OFF_H);
    unsigned short* rl    = (unsigned short*)(ws + OFF_RL);
    float*          hg    = (float*)(ws + OFF_HG);
    int*            rmap  = (int*)(ws + OFF_RMAP);
    unsigned short* Aloc  = (unsigned short*)d_out;   // scratch until finalize

    topk_kernel<<<dim3(NB), dim3(1024), 0, stream>>>(scores, sel, rmap);
    tcvt_all<<<dim3(504), dim3(256), 0, stream>>>(W1, W2, Wg1, W1t, W2t, Wg1t);
    gather_kernel<<<dim3(MSEL), dim3(256), 0, stream>>>(sel, hires, base, Aloc, Abase);
    gemm_mfma<0><<<dim3(8 * 10 * 6),  dim3(256), 0, stream>>>(Aloc, nullptr, W1t, b1, sel, scores, nullptr, h);
    gemm_mfma<1><<<dim3(8 * 10 * 12), dim3(256), 0, stream>>>(h, nullptr, W2t, b2, sel, scores, nullptr, rl);
    gemm_mfma<2><<<dim3(8 * 10 * 6),  dim3(256), 0, stream>>>(Abase, rl, Wg1t, bg1, sel, scores, Wg1 + (uint64_t)1536 * HID, hg);
    finalize_kernel<<<dim3(NB * NTOK / 4), dim3(256), 0, stream>>>(rmap, hg, Wg2, bg2, base, rl, out);
}